// Round 10
// baseline (145.564 us; speedup 1.0000x reference)
//
#include <hip/hip_runtime.h>
#include <stdint.h>

#define UU 512
#define NHEAD 8
#define NB 8
#define NXX 1024
#define NYY 1024
#define SCALE_F 0.125f   // 1/sqrt(64)

typedef __bf16 bf16x8 __attribute__((ext_vector_type(8)));
typedef float f32x4 __attribute__((ext_vector_type(4)));
typedef unsigned short us4 __attribute__((ext_vector_type(4)));

__device__ __forceinline__ unsigned short f2bf(float f) {
  union { float f; uint32_t u; } v; v.f = f;
  return (unsigned short)((v.u + 0x7FFFu + ((v.u >> 16) & 1u)) >> 16);
}

// ---------------------------------------------------------------------------
// Mask dtype probe: u8 bool -> nonzero bytes at p%4==1; i32/f32 -> zero there.
__global__ void detect_mask(const unsigned char* __restrict__ m, int* __restrict__ det) {
  int t = threadIdx.x;
  int c1 = 0;
  for (int q = t; q < 16384; q += 256) c1 |= m[q * 4 + 1];
  if (c1) atomicOr(&det[0], 1);
}

// ---------------------------------------------------------------------------
// prep: blocks 0..127 pack W -> bf16 fragment-order Wp[ub][kb][lane][8]
//   (slot s = (ub*16+kb)*64 + l ; u = ub*16 + (l&15) ; k = kb*32 + (l>>4)*8).
// Blocks 128..2175: pack mask -> 1 bit/element  mb[(b*1024+n)*16 + m/64]
//   (u64 word w covers columns w*64..w*64+63). Each thread handles 16
//   consecutive elements (64B coalesced in i32/f32 mode, 16B in u8 mode),
//   builds a u16, LDS-assembles 4 u16 -> u64.
__global__ void prep_kernel(const float* __restrict__ W, unsigned short* __restrict__ Wp,
                            const void* __restrict__ maskp, const int* __restrict__ det,
                            unsigned long long* __restrict__ mb) {
  __shared__ unsigned short sm[256];
  int blk = blockIdx.x, t = threadIdx.x;
  if (blk < 128) {
    int s = blk * 256 + t;
    int ub = s >> 10, kb = (s >> 6) & 15, l = s & 63;
    int u = ub * 16 + (l & 15), k = kb * 32 + (l >> 4) * 8;
    const float* src = W + (size_t)u * UU + k;
    float4 a = *(const float4*)src;
    float4 bq = *(const float4*)(src + 4);
    uint4 o;
    o.x = (unsigned)f2bf(a.x) | ((unsigned)f2bf(a.y) << 16);
    o.y = (unsigned)f2bf(a.z) | ((unsigned)f2bf(a.w) << 16);
    o.z = (unsigned)f2bf(bq.x) | ((unsigned)f2bf(bq.y) << 16);
    o.w = (unsigned)f2bf(bq.z) | ((unsigned)f2bf(bq.w) << 16);
    *(uint4*)(Wp + (size_t)s * 8) = o;
    return;
  }
  int pb = blk - 128;                         // 0..2047
  size_t g = (size_t)pb * 256 + t;            // thread's 16-element group
  unsigned int bm = 0;
  if (det[0]) {                               // u8 bool elements
    uint4 v = *(const uint4*)((const unsigned char*)maskp + g * 16);
    unsigned int wd[4] = {v.x, v.y, v.z, v.w};
#pragma unroll
    for (int j = 0; j < 16; j++)
      bm |= (((wd[j >> 2] >> ((j & 3) * 8)) & 0xffu) != 0u) << j;
  } else {                                    // 4-byte elements (i32 or f32)
    const unsigned int* mp = (const unsigned int*)maskp + g * 16;
#pragma unroll
    for (int q = 0; q < 4; q++) {
      uint4 v = *(const uint4*)(mp + q * 4);
      unsigned int wd[4] = {v.x, v.y, v.z, v.w};
#pragma unroll
      for (int j = 0; j < 4; j++)
        bm |= (wd[j] != 0u) << (q * 4 + j);
    }
  }
  sm[t] = (unsigned short)bm;
  __syncthreads();
  if (t < 64) {
    unsigned long long w0 = sm[t * 4], w1 = sm[t * 4 + 1], w2 = sm[t * 4 + 2], w3 = sm[t * 4 + 3];
    mb[(size_t)pb * 64 + t] = w0 | (w1 << 16) | (w2 << 32) | (w3 << 48);
  }
}

// ---------------------------------------------------------------------------
// cv -> pc in MFMA-FRAGMENT-PACKED layout (unchanged from R9):
//   pc[bz][q16][h][kb][lane][8], slot = ((bz*64 + q16)*8 + h)*2 + kb.
__global__ __launch_bounds__(256, 2) void conv_fused(
    const float* __restrict__ x, const float* __restrict__ y,
    const unsigned short* __restrict__ Wp, unsigned short* __restrict__ pc) {
  __shared__ unsigned short xs[64 * 512];    // 64 KB
  int fl = blockIdx.x;
  int bz = fl & 15, nt = (fl >> 4) & 15, ut = fl >> 8;
  int b = bz & 7;
  const float* src = (bz >> 3) ? y : x;
  int n0 = nt * 64;
  int t = threadIdx.x, w = t >> 6, l = t & 63;
  int lane_m = l & 15, lane_g = l >> 4;

  {
    int cq = (t & 15) * 4;
    int i2b = (t >> 4) * 2;
    const float* gb = src + (size_t)b * UU * NXX + n0 + cq;
#pragma unroll
    for (int it = 0; it < 16; it++) {
      int i2 = i2b + it * 32;
      float4 va = *(const float4*)(gb + (size_t)i2 * NXX);
      float4 vb = *(const float4*)(gb + (size_t)(i2 + 1) * NXX);
      float fa[4] = {va.x, va.y, va.z, va.w};
      float fb[4] = {vb.x, vb.y, vb.z, vb.w};
#pragma unroll
      for (int j = 0; j < 4; j++) {
        int n = cq + j;
        unsigned int pk = (unsigned)f2bf(fa[j]) | ((unsigned)f2bf(fb[j]) << 16);
        int e = n * 512 + (i2 ^ ((n & 7) << 3));
        *(unsigned int*)&xs[e] = pk;
      }
    }
  }
  __syncthreads();

  int u0 = ut * 256 + w * 64;
  int ub0 = u0 >> 4;
  const unsigned short* wb0 = Wp + (size_t)l * 8;
  f32x4 acc[4][4] = {};
  bf16x8 aA[4], aB[4], bA[4], bB[4];

#define LOADW(Adst, Bdst, KB) do {                                            \
    _Pragma("unroll") for (int tu = 0; tu < 4; tu++)                          \
      Adst[tu] = *(const bf16x8*)(wb0 + ((size_t)(ub0 + tu) * 16 + (KB)) * 512); \
    _Pragma("unroll") for (int tn = 0; tn < 4; tn++) {                        \
      int nl_ = tn * 16 + lane_m;                                             \
      int ka_ = (KB) * 32 + lane_g * 8;                                       \
      Bdst[tn] = *(const bf16x8*)&xs[nl_ * 512 + (ka_ ^ ((nl_ & 7) << 3))];   \
    }                                                                         \
  } while (0)
#define DOMFMA(Ab, Bb) do {                                                   \
    _Pragma("unroll") for (int tn = 0; tn < 4; tn++)                          \
    _Pragma("unroll") for (int tu = 0; tu < 4; tu++)                          \
      acc[tn][tu] = __builtin_amdgcn_mfma_f32_16x16x32_bf16(Ab[tu], Bb[tn], acc[tn][tu], 0, 0, 0); \
  } while (0)

  LOADW(aA, bA, 0);
#pragma unroll
  for (int kp = 0; kp < 8; kp++) {
    LOADW(aB, bB, 2 * kp + 1);
    DOMFMA(aA, bA);
    if (kp < 7) LOADW(aA, bA, 2 * kp + 2);
    DOMFMA(aB, bB);
  }
#undef LOADW
#undef DOMFMA

  unsigned short* ob = pc + (size_t)bz * 64 * 8 * 2 * 512;
  int h = u0 >> 6;
  int e0 = 4 * (lane_g & 1);
#pragma unroll
  for (int tn = 0; tn < 4; tn++)
#pragma unroll
    for (int tu = 0; tu < 4; tu++) {
      int q16 = nt * 4 + tn;
      int kb = tu >> 1;
      int g = (2 * tu + (lane_g >> 1)) & 3;
      size_t slot = ((size_t)q16 * 8 + h) * 2 + kb;
      us4 pk;
      pk.x = f2bf(acc[tn][tu][0]); pk.y = f2bf(acc[tn][tu][1]);
      pk.z = f2bf(acc[tn][tu][2]); pk.w = f2bf(acc[tn][tu][3]);
      *(us4*)(ob + slot * 512 + (g * 16 + lane_m) * 8 + e0) = pk;
    }
}

// ---------------------------------------------------------------------------
// Block: (b, 64n, 64m), all 8 heads, 4 waves; wave: n-half (w&1), head-quad
// (w>>1). A/B frags = contiguous 1KB wave-loads from packed pc. Mask comes
// from the 1-bit bitfield: 512B staged to LDS, applied in-register; n_el via
// popcount on wave 0. No mask HBM traffic, minimal LDS, (256,4) occupancy.
__global__ __launch_bounds__(256, 4) void score_kernel(
    const unsigned short* __restrict__ pc, const unsigned long long* __restrict__ mb,
    float* __restrict__ part) {
  __shared__ unsigned long long msk[64];
  __shared__ float red[4][8];
  int fl = blockIdx.x;
  int b = fl & 7, rr = fl >> 3;
  int nt = rr & 15, mt = rr >> 4;
  int t = threadIdx.x, w = t >> 6, l = t & 63;
  int lane_m = l & 15, lane_g = l >> 4;
  int n0 = nt * 64, m0 = mt * 64;
  int nw0 = (w & 1) * 32, hq = (w >> 1) * 4;

  if (t < 64) msk[t] = mb[((size_t)b * NXX + n0 + t) * 16 + mt];
  __syncthreads();

  if (w == 0) {
    unsigned long long mv = msk[l];
    unsigned int cl = (unsigned int)__popcll(mv);
    for (int s = 1; s < 64; s <<= 1) cl += __shfl_xor(cl, s);
    if (l == 0) red[0][4] = (float)cl;
  } else if (l == 0) {
    red[w][4] = 0.f;
  }

  // per-thread mask row-words (broadcast LDS reads: 16 lanes share a row)
  unsigned long long mw[2][4];
#pragma unroll
  for (int tn = 0; tn < 2; tn++)
#pragma unroll
    for (int r = 0; r < 4; r++)
      mw[tn][r] = msk[nw0 + tn * 16 + 4 * lane_g + r] >> lane_m;

  int xq0 = (n0 + nw0) >> 4;
  int yq0 = m0 >> 4;
  const unsigned short* xpl = pc + ((size_t)b * 64) * 8 * 2 * 512 + (size_t)l * 8;
  const unsigned short* ypl = pc + ((size_t)(NB + b) * 64) * 8 * 2 * 512 + (size_t)l * 8;
  float hsv[4] = {0.f, 0.f, 0.f, 0.f};
#pragma unroll
  for (int hh = 0; hh < 4; hh++) {
    int h = hq + hh;
    bf16x8 afr[2][2], bfr[4][2];
#pragma unroll
    for (int tn = 0; tn < 2; tn++)
#pragma unroll
      for (int kb = 0; kb < 2; kb++)
        afr[tn][kb] = *(const bf16x8*)(xpl + ((((size_t)(xq0 + tn)) * 8 + h) * 2 + kb) * 512);
#pragma unroll
    for (int tm = 0; tm < 4; tm++)
#pragma unroll
      for (int kb = 0; kb < 2; kb++)
        bfr[tm][kb] = *(const bf16x8*)(ypl + ((((size_t)(yq0 + tm)) * 8 + h) * 2 + kb) * 512);
#pragma unroll
    for (int tn = 0; tn < 2; tn++)
#pragma unroll
      for (int tm = 0; tm < 4; tm++) {
        f32x4 acc = {};
        acc = __builtin_amdgcn_mfma_f32_16x16x32_bf16(afr[tn][0], bfr[tm][0], acc, 0, 0, 0);
        acc = __builtin_amdgcn_mfma_f32_16x16x32_bf16(afr[tn][1], bfr[tm][1], acc, 0, 0, 0);
#pragma unroll
        for (int r = 0; r < 4; r++) {
          float v = acc[r];
          v = v > 0.f ? v : 0.f;
          unsigned int bit = (unsigned int)(mw[tn][r] >> (tm * 16)) & 1u;
          hsv[hh] += bit ? v : 0.f;
        }
      }
  }
#pragma unroll
  for (int hh = 0; hh < 4; hh++) {
    float hs = hsv[hh];
    for (int s = 1; s < 64; s <<= 1) hs += __shfl_xor(hs, s);
    if (l == 0) red[w][hh] = hs;
  }
  __syncthreads();
  float* pb = part + (size_t)fl * 16;
  if (t < 8) {
    int q = t >> 2, hh = t & 3;
    pb[t] = red[q * 2][hh] + red[q * 2 + 1][hh];
  } else if (t == 8) {
    pb[8] = red[0][4] + red[1][4] + red[2][4] + red[3][4];
  }
}

// ---------------------------------------------------------------------------
// One block per b. Batch b's score blocks are fl = j*8 + b (fl&7==b), j=0..255.
__global__ __launch_bounds__(256) void finalize(
    const float* __restrict__ part, const float* __restrict__ fcw,
    const float* __restrict__ fcb, float* __restrict__ out) {
  __shared__ float red[4][9];
  int b = blockIdx.x;
  int t = threadIdx.x, w = t >> 6, l = t & 63;
  const float* pb = part + (size_t)(t * 8 + b) * 16;   // row fl = t*8+b
  float v[9];
#pragma unroll
  for (int j = 0; j < 9; j++) v[j] = pb[j];
#pragma unroll
  for (int j = 0; j < 9; j++) {
    float s = v[j];
    for (int ss = 1; ss < 64; ss <<= 1) s += __shfl_xor(s, ss);
    v[j] = s;
  }
  if (l == 0)
#pragma unroll
    for (int j = 0; j < 9; j++) red[w][j] = v[j];
  __syncthreads();
  if (t == 0) {
    float s = 0.f, cn = 0.f;
#pragma unroll
    for (int h = 0; h < NHEAD; h++)
      s += (red[0][h] + red[1][h] + red[2][h] + red[3][h]) * fcw[h];
    cn = red[0][8] + red[1][8] + red[2][8] + red[3][8];
    if (cn < 0.5f) cn = 1.f;
    out[b] = s * (SCALE_F / cn) + fcb[0];
  }
}

// ---------------------------------------------------------------------------
extern "C" void kernel_launch(void* const* d_in, const int* in_sizes, int n_in,
                              void* d_out, int out_size, void* d_ws, size_t ws_size,
                              hipStream_t stream) {
  const float* x = (const float*)d_in[0];
  const float* y = (const float*)d_in[1];
  const void* mask = d_in[2];
  const float* W = (const float*)d_in[3];
  const float* fcw = (const float*)d_in[4];
  const float* fcb = (const float*)d_in[5];
  float* out = (float*)d_out;
  char* ws = (char*)d_ws;

  unsigned short* pc = (unsigned short*)ws;                  // packed conv out, 16 MB
  unsigned short* Wp = (unsigned short*)(ws + (16u << 20));  // packed W bf16, 512 KB
  float* part = (float*)(ws + (16u << 20) + (512u << 10));   // [2048][16] f32, 128 KB
  unsigned long long* mb = (unsigned long long*)(ws + (16u << 20) + (640u << 10)); // 1 MB
  int* det = (int*)(ws + (16u << 20) + (1664u << 10));       // 1 i32

  hipMemsetAsync(det, 0, 64, stream);
  detect_mask<<<1, 256, 0, stream>>>((const unsigned char*)mask, det);
  prep_kernel<<<2176, 256, 0, stream>>>(W, Wp, mask, det, mb);
  conv_fused<<<512, 256, 0, stream>>>(x, y, Wp, pc);
  score_kernel<<<2048, 256, 0, stream>>>(pc, mb, part);
  finalize<<<NB, 256, 0, stream>>>(part, fcw, fcb, out);
}